// Round 13
// baseline (84.479 us; speedup 1.0000x reference)
//
#include <hip/hip_runtime.h>
#include <hip/hip_bf16.h>
#include <cstdint>
#include <cstddef>

typedef __attribute__((ext_vector_type(8))) short bf16x8;
typedef __attribute__((ext_vector_type(4))) float f32x4;

#define BATCH 8
#define NTOK 8192
#define LDIM 512
#define DDIM 128
#define NQ 16

static __device__ __forceinline__ short f2bf(float f) {
  uint32_t u = __float_as_uint(f);
  uint32_t r = u + 0x7fffu + ((u >> 16) & 1u); // RNE
  return (short)(r >> 16);
}

// hardware packed f32->bf16 (RNE)
static __device__ __forceinline__ bf16x8 cvt8(float4 a, float4 b) {
  union { uint32_t u[4]; bf16x8 v; } r;
  asm("v_cvt_pk_bf16_f32 %0, %1, %2" : "=v"(r.u[0]) : "v"(a.x), "v"(a.y));
  asm("v_cvt_pk_bf16_f32 %0, %1, %2" : "=v"(r.u[1]) : "v"(a.z), "v"(a.w));
  asm("v_cvt_pk_bf16_f32 %0, %1, %2" : "=v"(r.u[2]) : "v"(b.x), "v"(b.y));
  asm("v_cvt_pk_bf16_f32 %0, %1, %2" : "=v"(r.u[3]) : "v"(b.z), "v"(b.w));
  return r.v;
}

static __device__ __forceinline__ uint32_t cvt2(float a, float b) {
  uint32_t o;
  asm("v_cvt_pk_bf16_f32 %0, %1, %2" : "=v"(o) : "v"(a), "v"(b));
  return o;
}

// pad-mask accessor robust to bool-ABI (byteFlag=1: 1B/elem, 0: int32/elem)
static __device__ __forceinline__ bool is_pad(const void* pad, int byteFlag, int j) {
  return byteFlag ? (((const unsigned char*)pad)[j] != 0)
                  : (((const int*)pad)[j] != 0);
}

// ---------------- k0: repack W1 -> MFMA B-frag order bf16; block 0 detects bool ABI ----------
// wfrag[(c*8 + t)*64 + lane][i] = bf16( W1[c*32 + (lane>>4)*8 + i][t*16 + (lane&15)] )
__global__ __launch_bounds__(256) void k0_wfrag(const float* __restrict__ W1,
                                                short* __restrict__ wfrag,
                                                const unsigned int* __restrict__ pad_raw,
                                                int* __restrict__ flag) {
  int tid = blockIdx.x * blockDim.x + threadIdx.x;
  if (tid < 16 * 8 * 64) {
    int l = tid & 63;
    int t = (tid >> 6) & 7;
    int c = tid >> 9;
    int kbase = c * 32 + (l >> 4) * 8;
    int col = t * 16 + (l & 15);
    bf16x8 frag;
#pragma unroll
    for (int i = 0; i < 8; ++i) frag[i] = f2bf(W1[(size_t)(kbase + i) * DDIM + col]);
    ((bf16x8*)wfrag)[tid] = frag;
  }
  if (blockIdx.x == 0) {
    int any_gt1 = 0;
    for (int i = threadIdx.x; i < 16384; i += 256)
      if (pad_raw[i] > 1u) any_gt1 = 1;
    unsigned long long m = __ballot(any_gt1);
    __shared__ int s[4];
    if ((threadIdx.x & 63) == 0) s[threadIdx.x >> 6] = (m != 0ull) ? 1 : 0;
    __syncthreads();
    if (threadIdx.x == 0) flag[0] = (s[0] | s[1] | s[2] | s[3]);
  }
}

// ---------------- k1f: FUSED single-pass, BARRIER-FREE K-loop ----------------
// 64 rows/block, 256 thr (4 waves x 16 rows); grid 1024; LDS = 64KB slab + 1KB aux -> 2 blk/CU.
// W fragments register-double-buffered straight from global (L2-hot 128KB) -> no LDS dbuf,
// no __syncthreads in the K-loop. Slab retains bf16 x for the pooling phase (swizzled).
__global__ __launch_bounds__(256, 2) void k1_fused(const float* __restrict__ x,
                                                   const short* __restrict__ wfrag,
                                                   const float* __restrict__ W2,
                                                   const int* __restrict__ ids,
                                                   const void* __restrict__ pad,
                                                   const int* __restrict__ flag,
                                                   unsigned int* __restrict__ partial_bf,
                                                   float* __restrict__ wsum_p) {
  __shared__ __align__(16) char slab[65536]; // bf16 x slab [64 rows][512 cols], swizzled
  __shared__ float wt_l[64];
  __shared__ int qq_l[64];
  __shared__ int idx_l[64];
  __shared__ int off_l[17];

  const int tid = threadIdx.x, wave = tid >> 6, lane = tid & 63;
  const int g = lane >> 4;
  const int row = wave * 16 + (lane & 15); // local row this lane's A-frag covers
  const int rowB = blockIdx.x * 64;
  const float* xp = x + (size_t)(rowB + row) * LDIM + g * 8;
  const bf16x8* wfp = (const bf16x8*)wfrag + lane; // frag(c,t) = wfp[(c*8+t)*64]
  const int swz = (row & 7) << 4;

#define ALOAD(dst, c)                              \
  {                                                \
    dst[0] = *(const float4*)(xp + (c) * 32);      \
    dst[1] = *(const float4*)(xp + (c) * 32 + 4);  \
  }

  f32x4 acc[8];
#pragma unroll
  for (int t = 0; t < 8; ++t) acc[t] = (f32x4){0.f, 0.f, 0.f, 0.f};
  float4 avbuf[4][2];   // 4 x-chunks in flight
  bf16x8 wf[2][8];      // W register double-buffer

  ALOAD(avbuf[0], 0);
  ALOAD(avbuf[1], 1);
  ALOAD(avbuf[2], 2);
  ALOAD(avbuf[3], 3);
#pragma unroll
  for (int t = 0; t < 8; ++t) wf[0][t] = wfp[t * 64];

#pragma unroll
  for (int c = 0; c < 16; ++c) {
    bf16x8 af = cvt8(avbuf[c & 3][0], avbuf[c & 3][1]);
    // retain in slab: cols c*32+g*8..+8 of local row, swizzled (2-way write conflict = free)
    *(bf16x8*)(slab + (((row << 10) + c * 64 + g * 16) ^ swz)) = af;
    if (c < 15) {
#pragma unroll
      for (int t = 0; t < 8; ++t) wf[(c + 1) & 1][t] = wfp[((c + 1) * 8 + t) * 64];
    }
    if (c < 12) ALOAD(avbuf[c & 3], c + 4);
#pragma unroll
    for (int t = 0; t < 8; ++t)
      acc[t] = __builtin_amdgcn_mfma_f32_16x16x32_bf16(af, wf[c & 1][t], acc[t], 0, 0, 0);
  }
#undef ALOAD

  // ---- epilogue: scores -> weights ----
  // D layout: col = lane&15 (+16t), row(within wave16) = g*4 + r
  float w2v[8];
#pragma unroll
  for (int t = 0; t < 8; ++t) w2v[t] = W2[t * 16 + (lane & 15)];
  float asum[4] = {0.f, 0.f, 0.f, 0.f};
#pragma unroll
  for (int t = 0; t < 8; ++t) {
#pragma unroll
    for (int r = 0; r < 4; ++r) {
      float h = 1.f - 2.f / (__expf(2.f * acc[t][r]) + 1.f); // tanh
      asum[r] += h * w2v[t];
    }
  }
#pragma unroll
  for (int m = 1; m < 16; m <<= 1) {
#pragma unroll
    for (int r = 0; r < 4; ++r) asum[r] += __shfl_xor(asum[r], m, 64);
  }
  const int bfl = flag[0];
  if ((lane & 15) == 0) {
#pragma unroll
    for (int r = 0; r < 4; ++r) {
      int lr = wave * 16 + g * 4 + r;
      int grow = rowB + lr;
      wt_l[lr] = __expf(asum[r]); // unnormalized softmax weight (|A|<=||W2||_1~9, safe)
      qq_l[lr] = is_pad(pad, bfl, grow) ? 16 : ids[grow];
    }
  }
  __syncthreads(); // slab complete + wt/qq visible

  // ---- wave 0: deterministic grouping of 64 rows by q ----
  if (tid < 64) {
    int q0 = qq_l[tid];
    unsigned long long below = (1ull << tid) - 1ull;
    int pos = 0;
    for (int q = 0; q < 16; ++q) {
      if (tid == 0) off_l[q] = pos;
      unsigned long long m = __ballot(q0 == q);
      if (q0 == q) idx_l[pos + __popcll(m & below)] = tid;
      pos += __popcll(m);
    }
    if (tid == 0) off_l[16] = pos;
  }
  __syncthreads();

  // per-(block,q) weight sums (fixed order -> deterministic)
  if (tid < 16) {
    float s = 0.f;
    for (int e = off_l[tid]; e < off_l[tid + 1]; ++e) s += wt_l[idx_l[e]];
    wsum_p[blockIdx.x * 16 + tid] = s;
  }

  // ---- pooling from LDS slab: thread owns cols 2*tid, 2*tid+1 ----
  const int colb = tid * 4; // byte offset of col pair within a row (pre-swizzle)
#pragma unroll 1
  for (int q = 0; q < 16; ++q) {
    int e0 = off_l[q], e1 = off_l[q + 1];
    float ax = 0.f, ay = 0.f;
    for (int e = e0; e < e1; ++e) {
      int r = idx_l[e];
      uint32_t u = *(const uint32_t*)(slab + (((r << 10) + colb) ^ ((r & 7) << 4)));
      float lo = __uint_as_float(u << 16);
      float hi = __uint_as_float(u & 0xffff0000u);
      float wt = wt_l[r];
      ax = fmaf(wt, lo, ax);
      ay = fmaf(wt, hi, ay);
    }
    partial_bf[(size_t)(blockIdx.x * 16 + q) * 256 + tid] = cvt2(ax, ay);
  }
}

// ---------------- k4: reduce 128 block-partials per (b,q), normalize ----------------
__global__ __launch_bounds__(256) void k4_reduce(const unsigned int* __restrict__ partial_bf,
                                                 const float* __restrict__ wsum_p,
                                                 float* __restrict__ out) {
  int b = blockIdx.x >> 4, q = blockIdx.x & 15;
  int tid = threadIdx.x;
  float ws = 0.f;
#pragma unroll 8
  for (int t = 0; t < 128; ++t) ws += wsum_p[(b * 128 + t) * 16 + q];
  float px = 0.f, py = 0.f;
#pragma unroll 4
  for (int t = 0; t < 128; ++t) {
    uint32_t u = partial_bf[(size_t)((b * 128 + t) * 16 + q) * 256 + tid];
    px += __uint_as_float(u << 16);
    py += __uint_as_float(u & 0xffff0000u);
  }
  float inv = (ws > 0.f) ? (1.f / ws) : 0.f;
  float2 o = {px * inv, py * inv};
  ((float2*)out)[(size_t)(b * 16 + q) * 256 + tid] = o;
}

extern "C" void kernel_launch(void* const* d_in, const int* in_sizes, int n_in,
                              void* d_out, int out_size, void* d_ws, size_t ws_size,
                              hipStream_t stream) {
  const float* x = (const float*)d_in[0];
  const float* W1 = (const float*)d_in[1];
  const float* W2 = (const float*)d_in[2];
  const int* ids = (const int*)d_in[3];
  const void* pad = d_in[4]; // bool ABI detected at runtime
  float* out = (float*)d_out;

  char* ws = (char*)d_ws;
  short* wfrag = (short*)ws;                            // 131072 B
  int* flag = (int*)(ws + 131072);                      // 4 B
  float* wsum_p = (float*)(ws + 131328);                // 1024*16*4 = 65536 B
  unsigned int* partial_bf = (unsigned int*)(ws + 196864); // 1024*16*256*4 = 16 MB

  hipLaunchKernelGGL(k0_wfrag, dim3(32), dim3(256), 0, stream,
                     W1, wfrag, (const unsigned int*)pad, flag);
  hipLaunchKernelGGL(k1_fused, dim3((BATCH * NTOK) / 64), dim3(256), 0, stream,
                     x, wfrag, W2, ids, pad, flag, partial_bf, wsum_p);
  hipLaunchKernelGGL(k4_reduce, dim3(BATCH * NQ), dim3(256), 0, stream,
                     partial_bf, wsum_p, out);
}

// Round 14
// 76.188 us; speedup vs baseline: 1.1088x; 1.1088x over previous
//
#include <hip/hip_runtime.h>
#include <hip/hip_bf16.h>
#include <cstdint>
#include <cstddef>

typedef __attribute__((ext_vector_type(8))) short bf16x8;
typedef __attribute__((ext_vector_type(4))) float f32x4;

#define BATCH 8
#define NTOK 8192
#define LDIM 512
#define DDIM 128
#define NQ 16

static __device__ __forceinline__ short f2bf(float f) {
  uint32_t u = __float_as_uint(f);
  uint32_t r = u + 0x7fffu + ((u >> 16) & 1u); // RNE
  return (short)(r >> 16);
}

// hardware packed f32->bf16 (RNE)
static __device__ __forceinline__ bf16x8 cvt8(float4 a, float4 b) {
  union { uint32_t u[4]; bf16x8 v; } r;
  asm("v_cvt_pk_bf16_f32 %0, %1, %2" : "=v"(r.u[0]) : "v"(a.x), "v"(a.y));
  asm("v_cvt_pk_bf16_f32 %0, %1, %2" : "=v"(r.u[1]) : "v"(a.z), "v"(a.w));
  asm("v_cvt_pk_bf16_f32 %0, %1, %2" : "=v"(r.u[2]) : "v"(b.x), "v"(b.y));
  asm("v_cvt_pk_bf16_f32 %0, %1, %2" : "=v"(r.u[3]) : "v"(b.z), "v"(b.w));
  return r.v;
}

static __device__ __forceinline__ uint32_t cvt2(float a, float b) {
  uint32_t o;
  asm("v_cvt_pk_bf16_f32 %0, %1, %2" : "=v"(o) : "v"(a), "v"(b));
  return o;
}

static __device__ __forceinline__ float bf2f(unsigned short u) {
  return __uint_as_float(((uint32_t)u) << 16);
}

// pad-mask accessor robust to bool-ABI (byteFlag=1: 1B/elem, 0: int32/elem)
static __device__ __forceinline__ bool is_pad(const void* pad, int byteFlag, int j) {
  return byteFlag ? (((const unsigned char*)pad)[j] != 0)
                  : (((const int*)pad)[j] != 0);
}

// ---------------- k0: repack W1 -> MFMA B-frag order bf16; block 0 detects bool ABI ----------
// wfrag[(c*8 + t)*64 + lane][i] = bf16( W1[c*32 + (lane>>4)*8 + i][t*16 + (lane&15)] )
__global__ __launch_bounds__(256) void k0_wfrag(const float* __restrict__ W1,
                                                short* __restrict__ wfrag,
                                                const unsigned int* __restrict__ pad_raw,
                                                int* __restrict__ flag) {
  int tid = blockIdx.x * blockDim.x + threadIdx.x;
  if (tid < 16 * 8 * 64) {
    int l = tid & 63;
    int t = (tid >> 6) & 7;
    int c = tid >> 9;
    int kbase = c * 32 + (l >> 4) * 8;
    int col = t * 16 + (l & 15);
    bf16x8 frag;
#pragma unroll
    for (int i = 0; i < 8; ++i) frag[i] = f2bf(W1[(size_t)(kbase + i) * DDIM + col]);
    ((bf16x8*)wfrag)[tid] = frag;
  }
  if (blockIdx.x == 0) {
    int any_gt1 = 0;
    for (int i = threadIdx.x; i < 16384; i += 256)
      if (pad_raw[i] > 1u) any_gt1 = 1;
    unsigned long long m = __ballot(any_gt1);
    __shared__ int s[4];
    if ((threadIdx.x & 63) == 0) s[threadIdx.x >> 6] = (m != 0ull) ? 1 : 0;
    __syncthreads();
    if (threadIdx.x == 0) flag[0] = (s[0] | s[1] | s[2] | s[3]);
  }
}

// ---------------- k1f: FUSED single-pass; wave-per-q ds_read_b128 pooling tail ------------
// 64 rows/block, 256 thr (4 waves x 16 rows); grid 1024; LDS = 64KB slab + aux -> 2 blk/CU.
// K-loop: barrier-free, W frags register-double-buffered from L2-hot wfrag (r13, verified).
// Tail: wave w owns q in {w, w+4, w+8, w+12}; per entry ONE ds_read_b128 of the slab row
// (lane L -> cols 8L..8L+8 via the same XOR involution) + 16 unpack-fmas. ~20x less serial
// latency than the r10/r13 per-thread gather tail.
__global__ __launch_bounds__(256, 2) void k1_fused(const float* __restrict__ x,
                                                   const short* __restrict__ wfrag,
                                                   const float* __restrict__ W2,
                                                   const int* __restrict__ ids,
                                                   const void* __restrict__ pad,
                                                   const int* __restrict__ flag,
                                                   unsigned int* __restrict__ partial_bf,
                                                   float* __restrict__ wsum_p) {
  __shared__ __align__(16) char slab[65536]; // bf16 x slab [64 rows][512 cols], swizzled
  __shared__ float wt_l[64];
  __shared__ int qq_l[64];
  __shared__ int idx_l[64];
  __shared__ int off_l[17];

  const int tid = threadIdx.x, wave = tid >> 6, lane = tid & 63;
  const int g = lane >> 4;
  const int row = wave * 16 + (lane & 15); // local row this lane's A-frag covers
  const int rowB = blockIdx.x * 64;
  const float* xp = x + (size_t)(rowB + row) * LDIM + g * 8;
  const bf16x8* wfp = (const bf16x8*)wfrag + lane; // frag(c,t) = wfp[(c*8+t)*64]
  const int swz = (row & 7) << 4;

#define ALOAD(dst, c)                              \
  {                                                \
    dst[0] = *(const float4*)(xp + (c) * 32);      \
    dst[1] = *(const float4*)(xp + (c) * 32 + 4);  \
  }

  f32x4 acc[8];
#pragma unroll
  for (int t = 0; t < 8; ++t) acc[t] = (f32x4){0.f, 0.f, 0.f, 0.f};
  float4 avbuf[4][2];   // 4 x-chunks in flight
  bf16x8 wf[2][8];      // W register double-buffer

  ALOAD(avbuf[0], 0);
  ALOAD(avbuf[1], 1);
  ALOAD(avbuf[2], 2);
  ALOAD(avbuf[3], 3);
#pragma unroll
  for (int t = 0; t < 8; ++t) wf[0][t] = wfp[t * 64];

#pragma unroll
  for (int c = 0; c < 16; ++c) {
    bf16x8 af = cvt8(avbuf[c & 3][0], avbuf[c & 3][1]);
    // retain in slab: cols c*32+g*8..+8 of local row, swizzled (2-way write conflict = free)
    *(bf16x8*)(slab + (((row << 10) + c * 64 + g * 16) ^ swz)) = af;
    if (c < 15) {
#pragma unroll
      for (int t = 0; t < 8; ++t) wf[(c + 1) & 1][t] = wfp[((c + 1) * 8 + t) * 64];
    }
    if (c < 12) ALOAD(avbuf[c & 3], c + 4);
#pragma unroll
    for (int t = 0; t < 8; ++t)
      acc[t] = __builtin_amdgcn_mfma_f32_16x16x32_bf16(af, wf[c & 1][t], acc[t], 0, 0, 0);
  }
#undef ALOAD

  // ---- epilogue: scores -> weights ----
  // D layout: col = lane&15 (+16t), row(within wave16) = g*4 + r
  float w2v[8];
#pragma unroll
  for (int t = 0; t < 8; ++t) w2v[t] = W2[t * 16 + (lane & 15)];
  float asum[4] = {0.f, 0.f, 0.f, 0.f};
#pragma unroll
  for (int t = 0; t < 8; ++t) {
#pragma unroll
    for (int r = 0; r < 4; ++r) {
      float h = 1.f - 2.f / (__expf(2.f * acc[t][r]) + 1.f); // tanh
      asum[r] += h * w2v[t];
    }
  }
#pragma unroll
  for (int m = 1; m < 16; m <<= 1) {
#pragma unroll
    for (int r = 0; r < 4; ++r) asum[r] += __shfl_xor(asum[r], m, 64);
  }
  const int bfl = flag[0];
  if ((lane & 15) == 0) {
#pragma unroll
    for (int r = 0; r < 4; ++r) {
      int lr = wave * 16 + g * 4 + r;
      int grow = rowB + lr;
      wt_l[lr] = __expf(asum[r]); // unnormalized softmax weight (|A|<=||W2||_1~9, safe)
      qq_l[lr] = is_pad(pad, bfl, grow) ? 16 : ids[grow];
    }
  }
  __syncthreads(); // slab complete + wt/qq visible

  // ---- wave 0: deterministic grouping of 64 rows by q ----
  if (tid < 64) {
    int q0 = qq_l[tid];
    unsigned long long below = (1ull << tid) - 1ull;
    int pos = 0;
    for (int q = 0; q < 16; ++q) {
      if (tid == 0) off_l[q] = pos;
      unsigned long long m = __ballot(q0 == q);
      if (q0 == q) idx_l[pos + __popcll(m & below)] = tid;
      pos += __popcll(m);
    }
    if (tid == 0) off_l[16] = pos;
  }
  __syncthreads();

  // per-(block,q) weight sums (fixed order -> deterministic)
  if (tid < 16) {
    float s = 0.f;
    for (int e = off_l[tid]; e < off_l[tid + 1]; ++e) s += wt_l[idx_l[e]];
    wsum_p[blockIdx.x * 16 + tid] = s;
  }

  // ---- pooling tail: wave w handles q = w + 4i; one ds_read_b128 per entry ----
  float accq[4][8]; // accq[i][k]: q = wave + 4i, cols lane*8+k
#pragma unroll
  for (int i = 0; i < 4; ++i)
#pragma unroll
    for (int k = 0; k < 8; ++k) accq[i][k] = 0.f;

#pragma unroll
  for (int i = 0; i < 4; ++i) {
    const int q = wave + i * 4;
    const int e0 = off_l[q], e1 = off_l[q + 1];
    for (int e = e0; e < e1; ++e) {
      int r = idx_l[e];
      float wt = wt_l[r];
      // lane L reads physical (L*16)^swz(r) within row r -> logical cols 8L..8L+8
      bf16x8 v = *(const bf16x8*)(slab + (r << 10) + ((lane << 4) ^ ((r & 7) << 4)));
#pragma unroll
      for (int k = 0; k < 8; ++k)
        accq[i][k] = fmaf(wt, bf2f((unsigned short)v[k]), accq[i][k]);
    }
  }
#pragma unroll
  for (int i = 0; i < 4; ++i) {
    const int q = wave + i * 4;
    uint4 o;
    o.x = cvt2(accq[i][0], accq[i][1]);
    o.y = cvt2(accq[i][2], accq[i][3]);
    o.z = cvt2(accq[i][4], accq[i][5]);
    o.w = cvt2(accq[i][6], accq[i][7]);
    *(uint4*)(partial_bf + (size_t)(blockIdx.x * 16 + q) * 256 + lane * 4) = o;
  }
}

// ---------------- k4: reduce 128 block-partials per (b,q), normalize ----------------
__global__ __launch_bounds__(256) void k4_reduce(const unsigned int* __restrict__ partial_bf,
                                                 const float* __restrict__ wsum_p,
                                                 float* __restrict__ out) {
  int b = blockIdx.x >> 4, q = blockIdx.x & 15;
  int tid = threadIdx.x;
  float ws = 0.f;
#pragma unroll 8
  for (int t = 0; t < 128; ++t) ws += wsum_p[(b * 128 + t) * 16 + q];
  float px = 0.f, py = 0.f;
#pragma unroll 4
  for (int t = 0; t < 128; ++t) {
    uint32_t u = partial_bf[(size_t)((b * 128 + t) * 16 + q) * 256 + tid];
    px += __uint_as_float(u << 16);
    py += __uint_as_float(u & 0xffff0000u);
  }
  float inv = (ws > 0.f) ? (1.f / ws) : 0.f;
  float2 o = {px * inv, py * inv};
  ((float2*)out)[(size_t)(b * 16 + q) * 256 + tid] = o;
}

extern "C" void kernel_launch(void* const* d_in, const int* in_sizes, int n_in,
                              void* d_out, int out_size, void* d_ws, size_t ws_size,
                              hipStream_t stream) {
  const float* x = (const float*)d_in[0];
  const float* W1 = (const float*)d_in[1];
  const float* W2 = (const float*)d_in[2];
  const int* ids = (const int*)d_in[3];
  const void* pad = d_in[4]; // bool ABI detected at runtime
  float* out = (float*)d_out;

  char* ws = (char*)d_ws;
  short* wfrag = (short*)ws;                            // 131072 B
  int* flag = (int*)(ws + 131072);                      // 4 B
  float* wsum_p = (float*)(ws + 131328);                // 1024*16*4 = 65536 B
  unsigned int* partial_bf = (unsigned int*)(ws + 196864); // 1024*16*256*4 = 16 MB

  hipLaunchKernelGGL(k0_wfrag, dim3(32), dim3(256), 0, stream,
                     W1, wfrag, (const unsigned int*)pad, flag);
  hipLaunchKernelGGL(k1_fused, dim3((BATCH * NTOK) / 64), dim3(256), 0, stream,
                     x, wfrag, W2, ids, pad, flag, partial_bf, wsum_p);
  hipLaunchKernelGGL(k4_reduce, dim3(BATCH * NQ), dim3(256), 0, stream,
                     partial_bf, wsum_p, out);
}